// Round 5
// baseline (336.293 us; speedup 1.0000x reference)
//
#include <hip/hip_runtime.h>
#include <hip/hip_bf16.h>

typedef __attribute__((ext_vector_type(8))) short bf16x8;
typedef __attribute__((ext_vector_type(4))) short s16x4;
typedef __attribute__((ext_vector_type(4))) float f32x4;

#define LDS_XS   136       // X chunk row stride (shorts): 128 + 8 pad
#define LDS_QKS  136       // QK row stride: 128 + 8
#define LDS_VTS  72        // Vt row stride: 64 + 8
#define LDS_PTS  20        // P^T row stride: 16 + 4
#define OFF_QK   0         // X-stage region aliases QK (X dead before QKV write)
#define OFF_VT   8704      // 64*136
#define OFF_PT   13312     // +64*72; per-wave 1280 shorts
#define LDS_TOT  18432     // 36,864 B -> 4 blocks/CU

__device__ __forceinline__ short f2b(float f) {
    __hip_bfloat16 h = __float2bfloat16(f);
    return __builtin_bit_cast(short, h);
}

__global__ void cvt_weights(const float* __restrict__ W1, const float* __restrict__ W2,
                            short* __restrict__ w1b, short* __restrict__ w2b) {
    int i = blockIdx.x * 256 + threadIdx.x;
    if (i < 192 * 768) w1b[i] = f2b(W1[i]);
    if (i < 768 * 64)  w2b[i] = f2b(W2[i]);
}

template<bool WSB>
__device__ __forceinline__ bf16x8 loadW(const short* __restrict__ wb,
                                        const float* __restrict__ wf, int off) {
    if (WSB) {
        return *(const bf16x8*)(wb + off);
    } else {
        f32x4 a = *(const f32x4*)(wf + off);
        f32x4 b = *(const f32x4*)(wf + off + 4);
        bf16x8 r;
        r[0] = f2b(a[0]); r[1] = f2b(a[1]); r[2] = f2b(a[2]); r[3] = f2b(a[3]);
        r[4] = f2b(b[0]); r[5] = f2b(b[1]); r[6] = f2b(b[2]); r[7] = f2b(b[3]);
        return r;
    }
}

// ============ Kernel A: proj1 + attention, Y -> ws (bf16 [131072][64]) ============
template<bool WSB>
__global__ __launch_bounds__(256, 4)
void qkv_attn(const float* __restrict__ x, const float* __restrict__ W1f,
              const float* __restrict__ b1v, const short* __restrict__ W1b,
              short* __restrict__ Yg) {
    __shared__ __align__(16) short lds[LDS_TOT];
    const int tid  = threadIdx.x;
    const int wid  = tid >> 6;
    const int lane = tid & 63;
    const int g    = lane >> 4;
    const int c    = lane & 15;
    const int win  = blockIdx.x;
    const float* xg = x + (size_t)win * (64 * 768);
    const f32x4 zero4 = {0.f, 0.f, 0.f, 0.f};

    f32x4 acc1[12];
    #pragma unroll
    for (int i = 0; i < 12; ++i) acc1[i] = zero4;

    f32x4 xr[8];
    #pragma unroll
    for (int i = 0; i < 8; ++i) {
        int idx = i * 256 + tid;
        xr[i] = *(const f32x4*)(xg + (idx >> 5) * 768 + (idx & 31) * 4);
    }

    #pragma unroll 1
    for (int kc = 0; kc < 6; ++kc) {
        if (kc) __syncthreads();
        #pragma unroll
        for (int i = 0; i < 8; ++i) {
            int idx = i * 256 + tid;
            s16x4 sv;
            sv[0] = f2b(xr[i][0]); sv[1] = f2b(xr[i][1]);
            sv[2] = f2b(xr[i][2]); sv[3] = f2b(xr[i][3]);
            *(s16x4*)&lds[(idx >> 5) * LDS_XS + (idx & 31) * 4] = sv;
        }
        __syncthreads();
        if (kc < 5) {
            #pragma unroll
            for (int i = 0; i < 8; ++i) {
                int idx = i * 256 + tid;
                xr[i] = *(const f32x4*)(xg + (idx >> 5) * 768 + (kc + 1) * 128 + (idx & 31) * 4);
            }
        }
        #pragma unroll
        for (int k8 = 0; k8 < 4; ++k8) {
            int kk = k8 * 32 + 8 * g;
            bf16x8 a[4];
            #pragma unroll
            for (int rt = 0; rt < 4; ++rt)
                a[rt] = *(const bf16x8*)&lds[(16 * rt + c) * LDS_XS + kk];
            #pragma unroll
            for (int oi = 0; oi < 3; ++oi) {
                int ot = wid + 4 * oi;
                bf16x8 b = loadW<WSB>(W1b, W1f, (16 * ot + c) * 768 + kc * 128 + kk);
                #pragma unroll
                for (int rt = 0; rt < 4; ++rt)
                    acc1[rt * 3 + oi] = __builtin_amdgcn_mfma_f32_16x16x32_bf16(
                        a[rt], b, acc1[rt * 3 + oi], 0, 0, 0);
            }
        }
    }
    __syncthreads();   // X region dead; QK region aliases it

    #pragma unroll
    for (int oi = 0; oi < 3; ++oi) {
        int ot = wid + 4 * oi;
        int o  = 16 * ot + c;
        float bias = b1v[o];
        #pragma unroll
        for (int rt = 0; rt < 4; ++rt) {
            f32x4 v = acc1[rt * 3 + oi];
            if (oi < 2) {
                #pragma unroll
                for (int r = 0; r < 4; ++r)
                    lds[OFF_QK + (16 * rt + 4 * g + r) * LDS_QKS + o] = f2b(v[r] + bias);
            } else {
                int d = o - 128;
                s16x4 sv;
                sv[0] = f2b(v[0] + bias); sv[1] = f2b(v[1] + bias);
                sv[2] = f2b(v[2] + bias); sv[3] = f2b(v[3] + bias);
                *(s16x4*)&lds[OFF_VT + d * LDS_VTS + 16 * rt + 4 * g] = sv;
            }
        }
    }
    __syncthreads();

    f32x4 sc[4];
    #pragma unroll
    for (int mt = 0; mt < 4; ++mt) sc[mt] = zero4;
    #pragma unroll
    for (int ks = 0; ks < 2; ++ks) {
        bf16x8 aq = *(const bf16x8*)&lds[OFF_QK + (16 * wid + c) * LDS_QKS + 32 * ks + 8 * g];
        #pragma unroll
        for (int mt = 0; mt < 4; ++mt) {
            bf16x8 bk = *(const bf16x8*)&lds[OFF_QK + (16 * mt + c) * LDS_QKS + 64 + 32 * ks + 8 * g];
            sc[mt] = __builtin_amdgcn_mfma_f32_16x16x32_bf16(aq, bk, sc[mt], 0, 0, 0);
        }
    }

    float p[4][4];
    const float kS = 0.125f * 1.44269504088896f;
    #pragma unroll
    for (int r = 0; r < 4; ++r) {
        float m0 = fmaxf(fmaxf(sc[0][r], sc[1][r]), fmaxf(sc[2][r], sc[3][r]));
        m0 = fmaxf(m0, __shfl_xor(m0, 1));
        m0 = fmaxf(m0, __shfl_xor(m0, 2));
        m0 = fmaxf(m0, __shfl_xor(m0, 4));
        m0 = fmaxf(m0, __shfl_xor(m0, 8));
        float s0 = 0.f;
        float pr[4];
        #pragma unroll
        for (int mt = 0; mt < 4; ++mt) {
            pr[mt] = exp2f((sc[mt][r] - m0) * kS);
            s0 += pr[mt];
        }
        s0 += __shfl_xor(s0, 1);
        s0 += __shfl_xor(s0, 2);
        s0 += __shfl_xor(s0, 4);
        s0 += __shfl_xor(s0, 8);
        float inv = __builtin_amdgcn_rcpf(s0);
        #pragma unroll
        for (int mt = 0; mt < 4; ++mt) p[mt][r] = pr[mt] * inv;
    }

    const int ptb = OFF_PT + wid * 1280;
    #pragma unroll
    for (int mt = 0; mt < 4; ++mt) {
        s16x4 sv;
        sv[0] = f2b(p[mt][0]); sv[1] = f2b(p[mt][1]);
        sv[2] = f2b(p[mt][2]); sv[3] = f2b(p[mt][3]);
        *(s16x4*)&lds[ptb + (16 * mt + c) * LDS_PTS + 4 * g] = sv;
    }

    f32x4 y4[4];
    #pragma unroll
    for (int it = 0; it < 4; ++it) y4[it] = zero4;
    #pragma unroll
    for (int ks = 0; ks < 2; ++ks) {
        bf16x8 pb;
        #pragma unroll
        for (int j = 0; j < 8; ++j)
            pb[j] = lds[ptb + (32 * ks + 8 * g + j) * LDS_PTS + c];
        #pragma unroll
        for (int it = 0; it < 4; ++it) {
            bf16x8 av = *(const bf16x8*)&lds[OFF_VT + (16 * it + c) * LDS_VTS + 32 * ks + 8 * g];
            y4[it] = __builtin_amdgcn_mfma_f32_16x16x32_bf16(av, pb, y4[it], 0, 0, 0);
        }
    }
    // Y[q=16wid+c][d=16it+4g+r] -> global ws, bf16 [131072][64]
    short* yrow = Yg + ((size_t)win * 64 + 16 * wid + c) * 64;
    #pragma unroll
    for (int it = 0; it < 4; ++it) {
        s16x4 sv;
        sv[0] = f2b(y4[it][0]); sv[1] = f2b(y4[it][1]);
        sv[2] = f2b(y4[it][2]); sv[3] = f2b(y4[it][3]);
        *(s16x4*)&yrow[16 * it + 4 * g] = sv;
    }
}

// ============ Kernel B: out[M][768] = Y[M][64] @ W2^T + b2 (streaming GEMM) ============
template<bool WSB>
__global__ __launch_bounds__(256, 6)
void proj2_gemm(const short* __restrict__ Yg, const float* __restrict__ W2f,
                const short* __restrict__ W2b, const float* __restrict__ b2v,
                float* __restrict__ out) {
    const int tid  = threadIdx.x;
    const int wid  = tid >> 6;
    const int lane = tid & 63;
    const int g    = lane >> 4;
    const int c    = lane & 15;
    const int win  = blockIdx.x;
    const f32x4 zero4 = {0.f, 0.f, 0.f, 0.f};

    const short* yrow = Yg + ((size_t)win * 64 + 16 * wid) * 64;
    bf16x8 ay0 = *(const bf16x8*)(yrow + c * 64 + 8 * g);        // k = 0..31
    bf16x8 ay1 = *(const bf16x8*)(yrow + c * 64 + 32 + 8 * g);   // k = 32..63
    float* orow = out + ((size_t)win * 64 + 16 * wid) * 768;

    #pragma unroll 1
    for (int ch = 0; ch < 6; ++ch) {           // 6 chunks of 8 o-tiles (32 acc VGPRs)
        f32x4 a2[8];
        #pragma unroll
        for (int i = 0; i < 8; ++i) a2[i] = zero4;
        #pragma unroll
        for (int oi = 0; oi < 8; ++oi) {
            int off = (16 * (ch * 8 + oi) + c) * 64;
            bf16x8 bw0 = loadW<WSB>(W2b, W2f, off + 8 * g);
            a2[oi] = __builtin_amdgcn_mfma_f32_16x16x32_bf16(ay0, bw0, a2[oi], 0, 0, 0);
            bf16x8 bw1 = loadW<WSB>(W2b, W2f, off + 32 + 8 * g);
            a2[oi] = __builtin_amdgcn_mfma_f32_16x16x32_bf16(ay1, bw1, a2[oi], 0, 0, 0);
        }
        #pragma unroll
        for (int oi = 0; oi < 8; ++oi) {
            int o = 16 * (ch * 8 + oi) + c;
            float bias = b2v[o];
            #pragma unroll
            for (int r = 0; r < 4; ++r)
                orow[(size_t)(4 * g + r) * 768 + o] = a2[oi][r] + bias;
        }
    }
}

// ============ Fallback: fully fused (R4) for small ws ============
template<bool WSB>
__global__ __launch_bounds__(256, 3)
void tiny_att_fused(const float* __restrict__ x, const float* __restrict__ W1f,
                    const float* __restrict__ b1v, const float* __restrict__ W2f,
                    const float* __restrict__ b2v, const short* __restrict__ W1b,
                    const short* __restrict__ W2b, float* __restrict__ out) {
    __shared__ __align__(16) short lds[LDS_TOT];
    const int tid  = threadIdx.x;
    const int wid  = tid >> 6;
    const int lane = tid & 63;
    const int g    = lane >> 4;
    const int c    = lane & 15;
    const int win  = blockIdx.x;
    const float* xg = x + (size_t)win * (64 * 768);
    const f32x4 zero4 = {0.f, 0.f, 0.f, 0.f};

    f32x4 acc1[12];
    #pragma unroll
    for (int i = 0; i < 12; ++i) acc1[i] = zero4;
    #pragma unroll 1
    for (int kc = 0; kc < 6; ++kc) {
        if (kc) __syncthreads();
        #pragma unroll
        for (int i = 0; i < 8; ++i) {
            int idx = i * 256 + tid;
            f32x4 v = *(const f32x4*)(xg + (idx >> 5) * 768 + kc * 128 + (idx & 31) * 4);
            s16x4 sv;
            sv[0] = f2b(v[0]); sv[1] = f2b(v[1]); sv[2] = f2b(v[2]); sv[3] = f2b(v[3]);
            *(s16x4*)&lds[(idx >> 5) * LDS_XS + (idx & 31) * 4] = sv;
        }
        __syncthreads();
        #pragma unroll
        for (int k8 = 0; k8 < 4; ++k8) {
            int kk = k8 * 32 + 8 * g;
            bf16x8 a[4];
            #pragma unroll
            for (int rt = 0; rt < 4; ++rt)
                a[rt] = *(const bf16x8*)&lds[(16 * rt + c) * LDS_XS + kk];
            #pragma unroll
            for (int oi = 0; oi < 3; ++oi) {
                int ot = wid + 4 * oi;
                bf16x8 b = loadW<WSB>(W1b, W1f, (16 * ot + c) * 768 + kc * 128 + kk);
                #pragma unroll
                for (int rt = 0; rt < 4; ++rt)
                    acc1[rt * 3 + oi] = __builtin_amdgcn_mfma_f32_16x16x32_bf16(
                        a[rt], b, acc1[rt * 3 + oi], 0, 0, 0);
            }
        }
    }
    __syncthreads();
    #pragma unroll
    for (int oi = 0; oi < 3; ++oi) {
        int ot = wid + 4 * oi;
        int o  = 16 * ot + c;
        float bias = b1v[o];
        #pragma unroll
        for (int rt = 0; rt < 4; ++rt) {
            f32x4 v = acc1[rt * 3 + oi];
            if (oi < 2) {
                #pragma unroll
                for (int r = 0; r < 4; ++r)
                    lds[OFF_QK + (16 * rt + 4 * g + r) * LDS_QKS + o] = f2b(v[r] + bias);
            } else {
                int d = o - 128;
                s16x4 sv;
                sv[0] = f2b(v[0] + bias); sv[1] = f2b(v[1] + bias);
                sv[2] = f2b(v[2] + bias); sv[3] = f2b(v[3] + bias);
                *(s16x4*)&lds[OFF_VT + d * LDS_VTS + 16 * rt + 4 * g] = sv;
            }
        }
    }
    __syncthreads();
    f32x4 sc[4];
    #pragma unroll
    for (int mt = 0; mt < 4; ++mt) sc[mt] = zero4;
    #pragma unroll
    for (int ks = 0; ks < 2; ++ks) {
        bf16x8 aq = *(const bf16x8*)&lds[OFF_QK + (16 * wid + c) * LDS_QKS + 32 * ks + 8 * g];
        #pragma unroll
        for (int mt = 0; mt < 4; ++mt) {
            bf16x8 bk = *(const bf16x8*)&lds[OFF_QK + (16 * mt + c) * LDS_QKS + 64 + 32 * ks + 8 * g];
            sc[mt] = __builtin_amdgcn_mfma_f32_16x16x32_bf16(aq, bk, sc[mt], 0, 0, 0);
        }
    }
    float p[4][4];
    const float kS = 0.125f * 1.44269504088896f;
    #pragma unroll
    for (int r = 0; r < 4; ++r) {
        float m0 = fmaxf(fmaxf(sc[0][r], sc[1][r]), fmaxf(sc[2][r], sc[3][r]));
        m0 = fmaxf(m0, __shfl_xor(m0, 1));
        m0 = fmaxf(m0, __shfl_xor(m0, 2));
        m0 = fmaxf(m0, __shfl_xor(m0, 4));
        m0 = fmaxf(m0, __shfl_xor(m0, 8));
        float s0 = 0.f;
        float pr[4];
        #pragma unroll
        for (int mt = 0; mt < 4; ++mt) { pr[mt] = exp2f((sc[mt][r] - m0) * kS); s0 += pr[mt]; }
        s0 += __shfl_xor(s0, 1);
        s0 += __shfl_xor(s0, 2);
        s0 += __shfl_xor(s0, 4);
        s0 += __shfl_xor(s0, 8);
        float inv = __builtin_amdgcn_rcpf(s0);
        #pragma unroll
        for (int mt = 0; mt < 4; ++mt) p[mt][r] = pr[mt] * inv;
    }
    const int ptb = OFF_PT + wid * 1280;
    #pragma unroll
    for (int mt = 0; mt < 4; ++mt) {
        s16x4 sv;
        sv[0] = f2b(p[mt][0]); sv[1] = f2b(p[mt][1]);
        sv[2] = f2b(p[mt][2]); sv[3] = f2b(p[mt][3]);
        *(s16x4*)&lds[ptb + (16 * mt + c) * LDS_PTS + 4 * g] = sv;
    }
    f32x4 y4[4];
    #pragma unroll
    for (int it = 0; it < 4; ++it) y4[it] = zero4;
    #pragma unroll
    for (int ks = 0; ks < 2; ++ks) {
        bf16x8 pb;
        #pragma unroll
        for (int j = 0; j < 8; ++j)
            pb[j] = lds[ptb + (32 * ks + 8 * g + j) * LDS_PTS + c];
        #pragma unroll
        for (int it = 0; it < 4; ++it) {
            bf16x8 av = *(const bf16x8*)&lds[OFF_VT + (16 * it + c) * LDS_VTS + 32 * ks + 8 * g];
            y4[it] = __builtin_amdgcn_mfma_f32_16x16x32_bf16(av, pb, y4[it], 0, 0, 0);
        }
    }
    bf16x8 ay0, ay1;
    #pragma unroll
    for (int it = 0; it < 4; ++it) {   // repack y4 (d=16it+4g+r) into 2 k-frags via LDS
        s16x4 sv;
        sv[0] = f2b(y4[it][0]); sv[1] = f2b(y4[it][1]);
        sv[2] = f2b(y4[it][2]); sv[3] = f2b(y4[it][3]);
        *(s16x4*)&lds[ptb + c * LDS_PTS + 0] = sv;   // placeholder row reuse
        // direct repack instead below
    }
    {   // simple LDS transpose using PT region rows (wave-private)
        #pragma unroll
        for (int it = 0; it < 4; ++it) {
            s16x4 sv;
            sv[0] = f2b(y4[it][0]); sv[1] = f2b(y4[it][1]);
            sv[2] = f2b(y4[it][2]); sv[3] = f2b(y4[it][3]);
            *(s16x4*)&lds[ptb + c * 72 + 16 * it + 4 * g] = sv;
        }
        ay0 = *(const bf16x8*)&lds[ptb + c * 72 + 8 * g];
        ay1 = *(const bf16x8*)&lds[ptb + c * 72 + 32 + 8 * g];
    }
    float* orow = out + ((size_t)win * 64 + 16 * wid) * 768;
    #pragma unroll 1
    for (int ch = 0; ch < 6; ++ch) {
        f32x4 a2[8];
        #pragma unroll
        for (int i = 0; i < 8; ++i) a2[i] = zero4;
        #pragma unroll
        for (int oi = 0; oi < 8; ++oi) {
            int off = (16 * (ch * 8 + oi) + c) * 64;
            bf16x8 bw0 = loadW<WSB>(W2b, W2f, off + 8 * g);
            a2[oi] = __builtin_amdgcn_mfma_f32_16x16x32_bf16(ay0, bw0, a2[oi], 0, 0, 0);
            bf16x8 bw1 = loadW<WSB>(W2b, W2f, off + 32 + 8 * g);
            a2[oi] = __builtin_amdgcn_mfma_f32_16x16x32_bf16(ay1, bw1, a2[oi], 0, 0, 0);
        }
        #pragma unroll
        for (int oi = 0; oi < 8; ++oi) {
            int o = 16 * (ch * 8 + oi) + c;
            float bias = b2v[o];
            #pragma unroll
            for (int r = 0; r < 4; ++r)
                orow[(size_t)(4 * g + r) * 768 + o] = a2[oi][r] + bias;
        }
    }
}

extern "C" void kernel_launch(void* const* d_in, const int* in_sizes, int n_in,
                              void* d_out, int out_size, void* d_ws, size_t ws_size,
                              hipStream_t stream) {
    const float* x  = (const float*)d_in[0];
    const float* W1 = (const float*)d_in[1];
    const float* b1 = (const float*)d_in[2];
    const float* W2 = (const float*)d_in[3];
    const float* b2 = (const float*)d_in[4];
    float* out = (float*)d_out;
    const int nwin = in_sizes[0] / (64 * 768);   // 2048 windows
    const size_t need_w = (size_t)(192 * 768 + 768 * 64) * sizeof(short);
    const size_t need_y = (size_t)nwin * 64 * 64 * sizeof(short);
    if (ws_size >= need_w + need_y) {
        short* w1b = (short*)d_ws;
        short* w2b = w1b + 192 * 768;
        short* Yg  = w2b + 768 * 64;
        cvt_weights<<<576, 256, 0, stream>>>(W1, W2, w1b, w2b);
        qkv_attn<true><<<nwin, 256, 0, stream>>>(x, W1, b1, w1b, Yg);
        proj2_gemm<true><<<nwin, 256, 0, stream>>>(Yg, W2, w2b, b2, out);
    } else if (ws_size >= need_w) {
        short* w1b = (short*)d_ws;
        short* w2b = w1b + 192 * 768;
        cvt_weights<<<576, 256, 0, stream>>>(W1, W2, w1b, w2b);
        tiny_att_fused<true><<<nwin, 256, 0, stream>>>(x, W1, b1, W2, b2, w1b, w2b, out);
    } else {
        tiny_att_fused<false><<<nwin, 256, 0, stream>>>(x, W1, b1, W2, b2, nullptr, nullptr, out);
    }
}

// Round 6
// 252.627 us; speedup vs baseline: 1.3312x; 1.3312x over previous
//
#include <hip/hip_runtime.h>
#include <hip/hip_bf16.h>

typedef __attribute__((ext_vector_type(8))) short bf16x8;
typedef __attribute__((ext_vector_type(4))) short s16x4;
typedef __attribute__((ext_vector_type(4))) float f32x4;

// LDS layout (bytes):
//  [0, 32768)     X double-buffer: 2 x [64 rows][64 f32] LINEAR (global_load_lds dest),
//                 16B-chunk index XOR-swizzled on the SOURCE side (rule #21: both-sides)
//  [32768, 49152) QK bf16 [64][128] (Q cols 0..63, K cols 64..127)
//  post-proj1 the X region is aliased: VT [64][72]sh @ sh 0 ; PT per-wave @ sh 4608+wid*1280
#define XBUF(b)   ((b) * 16384)
#define QK_SH     16384
#define LDS_BYTES 49152

__device__ __forceinline__ short f2b(float f) {
    __hip_bfloat16 h = __float2bfloat16(f);
    return __builtin_bit_cast(short, h);
}

__global__ void cvt_weights(const float* __restrict__ W1, const float* __restrict__ W2,
                            short* __restrict__ w1b, short* __restrict__ w2b) {
    int i = blockIdx.x * 256 + threadIdx.x;
    if (i < 192 * 768) w1b[i] = f2b(W1[i]);
    if (i < 768 * 64)  w2b[i] = f2b(W2[i]);
}

template<bool WSB>
__device__ __forceinline__ bf16x8 loadW(const short* __restrict__ wb,
                                        const float* __restrict__ wf, int off) {
    if (WSB) {
        return *(const bf16x8*)(wb + off);
    } else {
        f32x4 a = *(const f32x4*)(wf + off);
        f32x4 b = *(const f32x4*)(wf + off + 4);
        bf16x8 r;
        r[0] = f2b(a[0]); r[1] = f2b(a[1]); r[2] = f2b(a[2]); r[3] = f2b(a[3]);
        r[4] = f2b(b[0]); r[5] = f2b(b[1]); r[6] = f2b(b[2]); r[7] = f2b(b[3]);
        return r;
    }
}

__device__ __forceinline__ void gload_lds16(const float* g, unsigned char* l) {
    __builtin_amdgcn_global_load_lds(
        (const __attribute__((address_space(1))) void*)g,
        (__attribute__((address_space(3))) void*)l, 16, 0, 0);
}

#define VMWAIT(n) asm volatile("s_waitcnt vmcnt(" #n ")" ::: "memory")

// Stage 64-col f32 chunk kc -> X buffer b. 4 calls/wave, LDS dest wave-uniform+linear.
// Source pre-swizzled: LDS 16B-slot s of row r holds global chunk (s ^ (r&15)).
#define STAGE_CHUNK(kc, b) do {                                                     \
    _Pragma("unroll")                                                               \
    for (int j = 0; j < 4; ++j) {                                                   \
        int rr = (wid * 4 + j) * 4 + (lane >> 4);                                   \
        int ss = lane & 15;                                                         \
        const float* gsrc = xg + rr * 768 + (kc) * 64 + ((ss ^ (rr & 15)) << 2);    \
        gload_lds16(gsrc, &L[XBUF(b) + (wid * 4 + j) * 1024]);                      \
    }                                                                               \
} while (0)

#define WPREF(kc, W) do {                                                           \
    _Pragma("unroll")                                                               \
    for (int ks = 0; ks < 2; ++ks)                                                  \
        _Pragma("unroll")                                                           \
        for (int oi = 0; oi < 3; ++oi)                                              \
            W[ks*3+oi] = loadW<WSB>(W1b, W1f,                                       \
                (16*(wid+4*oi)+c)*768 + (kc)*64 + ks*32 + 8*g);                     \
} while (0)

#define COMPUTE(kc, b, W) do {                                                      \
    const unsigned char* Lb = &L[XBUF(b)];                                          \
    _Pragma("unroll")                                                               \
    for (int ks = 0; ks < 2; ++ks) {                                                \
        bf16x8 a[4];                                                                \
        _Pragma("unroll")                                                           \
        for (int rt = 0; rt < 4; ++rt) {                                            \
            int r = 16*rt + c;                                                      \
            int s0 = (8*ks + 2*g) ^ (r & 15);                                       \
            int s1 = (8*ks + 2*g + 1) ^ (r & 15);                                   \
            f32x4 lo = *(const f32x4*)(Lb + r*256 + s0*16);                         \
            f32x4 hi = *(const f32x4*)(Lb + r*256 + s1*16);                         \
            a[rt][0]=f2b(lo[0]); a[rt][1]=f2b(lo[1]);                               \
            a[rt][2]=f2b(lo[2]); a[rt][3]=f2b(lo[3]);                               \
            a[rt][4]=f2b(hi[0]); a[rt][5]=f2b(hi[1]);                               \
            a[rt][6]=f2b(hi[2]); a[rt][7]=f2b(hi[3]);                               \
        }                                                                           \
        _Pragma("unroll")                                                           \
        for (int oi = 0; oi < 3; ++oi)                                              \
            _Pragma("unroll")                                                       \
            for (int rt = 0; rt < 4; ++rt)                                          \
                acc1[rt*3+oi] = __builtin_amdgcn_mfma_f32_16x16x32_bf16(            \
                    a[rt], W[ks*3+oi], acc1[rt*3+oi], 0, 0, 0);                     \
    }                                                                               \
} while (0)

// steady: need stg(kc) done; issued after it: W(kc)[6|12] + stg(kc+1)[4] -> vmcnt(10|16)
// kc=11: after stg(11): W(11)[6|12] -> vmcnt(6|12)
#define PIPE_ITER(kc, b, Wc, Wn) do {                                               \
    if ((kc) != 11) { if constexpr (WSB) VMWAIT(10); else VMWAIT(16); }             \
    else            { if constexpr (WSB) VMWAIT(6);  else VMWAIT(12); }             \
    __builtin_amdgcn_sched_barrier(0);                                              \
    __builtin_amdgcn_s_barrier();                                                   \
    __builtin_amdgcn_sched_barrier(0);                                              \
    COMPUTE(kc, b, Wc);                                                             \
    if ((kc) + 1 < 12) WPREF((kc)+1, Wn);                                           \
    asm volatile("s_waitcnt lgkmcnt(0)" ::: "memory");                              \
    __builtin_amdgcn_sched_barrier(0);                                              \
    __builtin_amdgcn_s_barrier();                                                   \
    __builtin_amdgcn_sched_barrier(0);                                              \
    if ((kc) + 2 < 12) STAGE_CHUNK((kc)+2, b);                                      \
} while (0)

template<bool WSB>
__global__ __launch_bounds__(256, 3)
void tiny_att(const float* __restrict__ x, const float* __restrict__ W1f,
              const float* __restrict__ b1v, const float* __restrict__ W2f,
              const float* __restrict__ b2v, const short* __restrict__ W1b,
              const short* __restrict__ W2b, float* __restrict__ out) {
    __shared__ __align__(16) unsigned char L[LDS_BYTES];
    short* S = (short*)L;
    const int tid  = threadIdx.x;
    const int wid  = tid >> 6;
    const int lane = tid & 63;
    const int g    = lane >> 4;
    const int c    = lane & 15;
    const int win  = blockIdx.x;
    const float* xg = x + (size_t)win * (64 * 768);
    const f32x4 zero4 = {0.f, 0.f, 0.f, 0.f};

    // ---------------- proj1: QKV[64][192] = X @ W1^T, async-pipelined ----------------
    f32x4 acc1[12];
    #pragma unroll
    for (int i = 0; i < 12; ++i) acc1[i] = zero4;

    bf16x8 Wa[6], Wb[6];
    STAGE_CHUNK(0, 0);
    STAGE_CHUNK(1, 1);
    WPREF(0, Wa);

    #pragma unroll 1
    for (int kc = 0; kc < 12; kc += 2) {
        PIPE_ITER(kc,     0, Wa, Wb);
        PIPE_ITER(kc + 1, 1, Wb, Wa);
    }
    __syncthreads();   // full drain; X region dead -> VT/PT alias it

    // ---------------- bias + QKV -> LDS ----------------
    #pragma unroll
    for (int oi = 0; oi < 3; ++oi) {
        int ot = wid + 4 * oi;
        int o  = 16 * ot + c;
        float bias = b1v[o];
        #pragma unroll
        for (int rt = 0; rt < 4; ++rt) {
            f32x4 v = acc1[rt * 3 + oi];
            if (oi < 2) {        // Q (o<64), K (64..127): rows [n][o], stride 128
                #pragma unroll
                for (int r = 0; r < 4; ++r)
                    S[QK_SH + (16 * rt + 4 * g + r) * 128 + o] = f2b(v[r] + bias);
            } else {             // V transposed: VT[d][n], stride 72, base 0
                int d = o - 128;
                s16x4 sv;
                sv[0] = f2b(v[0] + bias); sv[1] = f2b(v[1] + bias);
                sv[2] = f2b(v[2] + bias); sv[3] = f2b(v[3] + bias);
                *(s16x4*)&S[d * 72 + 16 * rt + 4 * g] = sv;
            }
        }
    }
    __syncthreads();

    // ---------------- S = Q K^T (wave: q-rows 16wid..16wid+15) ----------------
    f32x4 sc[4];
    #pragma unroll
    for (int mt = 0; mt < 4; ++mt) sc[mt] = zero4;
    #pragma unroll
    for (int ks = 0; ks < 2; ++ks) {
        bf16x8 aq = *(const bf16x8*)&S[QK_SH + (16 * wid + c) * 128 + 32 * ks + 8 * g];
        #pragma unroll
        for (int mt = 0; mt < 4; ++mt) {
            bf16x8 bk = *(const bf16x8*)&S[QK_SH + (16 * mt + c) * 128 + 64 + 32 * ks + 8 * g];
            sc[mt] = __builtin_amdgcn_mfma_f32_16x16x32_bf16(aq, bk, sc[mt], 0, 0, 0);
        }
    }

    // ---------------- softmax ----------------
    float p[4][4];
    const float kS = 0.125f * 1.44269504088896f;
    #pragma unroll
    for (int r = 0; r < 4; ++r) {
        float m0 = fmaxf(fmaxf(sc[0][r], sc[1][r]), fmaxf(sc[2][r], sc[3][r]));
        m0 = fmaxf(m0, __shfl_xor(m0, 1));
        m0 = fmaxf(m0, __shfl_xor(m0, 2));
        m0 = fmaxf(m0, __shfl_xor(m0, 4));
        m0 = fmaxf(m0, __shfl_xor(m0, 8));
        float s0 = 0.f;
        float pr[4];
        #pragma unroll
        for (int mt = 0; mt < 4; ++mt) { pr[mt] = exp2f((sc[mt][r] - m0) * kS); s0 += pr[mt]; }
        s0 += __shfl_xor(s0, 1);
        s0 += __shfl_xor(s0, 2);
        s0 += __shfl_xor(s0, 4);
        s0 += __shfl_xor(s0, 8);
        float inv = __builtin_amdgcn_rcpf(s0);
        #pragma unroll
        for (int mt = 0; mt < 4; ++mt) p[mt][r] = pr[mt] * inv;
    }

    // ---------------- P^T -> LDS (per-wave region, stride 20) ----------------
    const int ptb = 4608 + wid * 1280;
    #pragma unroll
    for (int mt = 0; mt < 4; ++mt) {
        s16x4 sv;
        sv[0] = f2b(p[mt][0]); sv[1] = f2b(p[mt][1]);
        sv[2] = f2b(p[mt][2]); sv[3] = f2b(p[mt][3]);
        *(s16x4*)&S[ptb + (16 * mt + c) * 20 + 4 * g] = sv;
    }

    // ---------------- Y^T = V^T @ P^T ----------------
    f32x4 y4[4];
    #pragma unroll
    for (int it = 0; it < 4; ++it) y4[it] = zero4;
    #pragma unroll
    for (int ks = 0; ks < 2; ++ks) {
        bf16x8 pb;
        #pragma unroll
        for (int j = 0; j < 8; ++j)
            pb[j] = S[ptb + (32 * ks + 8 * g + j) * 20 + c];
        #pragma unroll
        for (int it = 0; it < 4; ++it) {
            bf16x8 av = *(const bf16x8*)&S[(16 * it + c) * 72 + 32 * ks + 8 * g];
            y4[it] = __builtin_amdgcn_mfma_f32_16x16x32_bf16(av, pb, y4[it], 0, 0, 0);
        }
    }
    // Y repack via per-wave region (stride 72, 16B-aligned rows)
    #pragma unroll
    for (int it = 0; it < 4; ++it) {
        s16x4 sv;
        sv[0] = f2b(y4[it][0]); sv[1] = f2b(y4[it][1]);
        sv[2] = f2b(y4[it][2]); sv[3] = f2b(y4[it][3]);
        *(s16x4*)&S[ptb + c * 72 + 16 * it + 4 * g] = sv;
    }
    bf16x8 ay0 = *(const bf16x8*)&S[ptb + c * 72 + 8 * g];
    bf16x8 ay1 = *(const bf16x8*)&S[ptb + c * 72 + 32 + 8 * g];

    // ---------------- proj2: out[16 rows][768] = Y @ W2^T + b2 ----------------
    float* orow = out + ((size_t)win * 64 + 16 * wid) * 768;
    #pragma unroll 1
    for (int ch = 0; ch < 6; ++ch) {
        f32x4 a2[8];
        #pragma unroll
        for (int i = 0; i < 8; ++i) a2[i] = zero4;
        #pragma unroll
        for (int oi = 0; oi < 8; ++oi) {
            int off = (16 * (ch * 8 + oi) + c) * 64;
            bf16x8 bw0 = loadW<WSB>(W2b, W2f, off + 8 * g);
            a2[oi] = __builtin_amdgcn_mfma_f32_16x16x32_bf16(ay0, bw0, a2[oi], 0, 0, 0);
            bf16x8 bw1 = loadW<WSB>(W2b, W2f, off + 32 + 8 * g);
            a2[oi] = __builtin_amdgcn_mfma_f32_16x16x32_bf16(ay1, bw1, a2[oi], 0, 0, 0);
        }
        #pragma unroll
        for (int oi = 0; oi < 8; ++oi) {
            int o = 16 * (ch * 8 + oi) + c;
            float bias = b2v[o];
            #pragma unroll
            for (int r = 0; r < 4; ++r)
                orow[(size_t)(4 * g + r) * 768 + o] = a2[oi][r] + bias;
        }
    }
}

extern "C" void kernel_launch(void* const* d_in, const int* in_sizes, int n_in,
                              void* d_out, int out_size, void* d_ws, size_t ws_size,
                              hipStream_t stream) {
    const float* x  = (const float*)d_in[0];
    const float* W1 = (const float*)d_in[1];
    const float* b1 = (const float*)d_in[2];
    const float* W2 = (const float*)d_in[3];
    const float* b2 = (const float*)d_in[4];
    float* out = (float*)d_out;
    const int nwin = in_sizes[0] / (64 * 768);   // 2048 windows
    const size_t need = (size_t)(192 * 768 + 768 * 64) * sizeof(short);
    if (ws_size >= need) {
        short* w1b = (short*)d_ws;
        short* w2b = w1b + 192 * 768;
        cvt_weights<<<576, 256, 0, stream>>>(W1, W2, w1b, w2b);
        tiny_att<true><<<nwin, 256, 0, stream>>>(x, W1, b1, W2, b2, w1b, w2b, out);
    } else {
        tiny_att<false><<<nwin, 256, 0, stream>>>(x, W1, b1, W2, b2, nullptr, nullptr, out);
    }
}